// Round 8
// baseline (99.262 us; speedup 1.0000x reference)
//
#include <hip/hip_runtime.h>
#include <hip/hip_bf16.h>
#include <math.h>

#define TPB 256
constexpr int Bb = 8, Mm = 2048, Nn = 8192, HID = 128;

typedef __attribute__((ext_vector_type(8))) short short8;
typedef __attribute__((ext_vector_type(4))) float f32x4;
typedef __attribute__((ext_vector_type(2))) float f32x2;

__device__ __forceinline__ int vzero() { int v; asm("v_mov_b32 %0, 0" : "=v"(v)); return v; }
__device__ __forceinline__ float4 ldg4(const float* __restrict__ p, int idx4, int vz) {
  return ((const float4*)p)[idx4 + vz];
}
__device__ __forceinline__ unsigned short f2b(float x) {
  __hip_bfloat16 h = __float2bfloat16(x);
  return *reinterpret_cast<unsigned short*>(&h);
}
__device__ __forceinline__ f32x2 fma2(f32x2 a, f32x2 b, f32x2 c) {
  return __builtin_elementwise_fma(a, b, c);      // -> v_pk_fma_f32
}

// --- K0: pack fused weights Wf = W2^T·Wd into MFMA-B fragment order (bf16) ---
__global__ __launch_bounds__(TPB) void prep2_kernel(const float* __restrict__ W2,
    const float* __restrict__ b2, const float* __restrict__ Wd,
    const float* __restrict__ bd, unsigned short* __restrict__ Bpack,
    float* __restrict__ Cf) {
  int idx = blockIdx.x * TPB + threadIdx.x;   // 0..32767
  int f = idx >> 9, r = idx & 511, lane = r >> 3, j = r & 7;
  int chunk = f >> 4, ks = (f >> 2) & 3, n = f & 3;
  int k   = ks * 32 + (lane >> 4) * 8 + j;
  int col = chunk * 64 + n * 16 + (lane & 15);
  float acc = 0.f;
  for (int i = 0; i < HID; ++i)
    acc = fmaf(W2[i * HID + k], Wd[i * 256 + col], acc);
  Bpack[idx] = f2b(acc);
  if (idx < 256) {
    float c = bd[idx >> 1];
    for (int i = 0; i < HID; ++i) c = fmaf(b2[i], Wd[i * 256 + idx], c);
    Cf[idx] = c;
  }
}

// in-place: a = sorted-asc top-8 of union(a,b); a,b sorted-asc top-8 lists
__device__ __forceinline__ void mergeTop8(float a[8], const float b[8]) {
  float w[8];
  #pragma unroll
  for (int i = 0; i < 8; ++i) w[i] = fmaxf(a[i], b[7 - i]);
  #pragma unroll
  for (int i = 0; i < 4; ++i) {
    float lo = fminf(w[i], w[i + 4]); w[i + 4] = fmaxf(w[i], w[i + 4]); w[i] = lo;
  }
  #pragma unroll
  for (int g = 0; g < 8; g += 4)
    #pragma unroll
    for (int i = 0; i < 2; ++i) {
      float lo = fminf(w[g + i], w[g + i + 2]);
      w[g + i + 2] = fmaxf(w[g + i], w[g + i + 2]); w[g + i] = lo;
    }
  #pragma unroll
  for (int i = 0; i < 8; i += 2) {
    float lo = fminf(w[i], w[i + 1]); w[i + 1] = fmaxf(w[i], w[i + 1]); w[i] = lo;
  }
  #pragma unroll
  for (int i = 0; i < 8; ++i) a[i] = w[i];
}
__device__ __forceinline__ float t8of(const float a[8], const float b[8]) {
  float t = fmaxf(a[0], b[7]);
  #pragma unroll
  for (int i = 1; i < 8; ++i) t = fminf(t, fmaxf(a[i], b[7 - i]));
  return t;
}

#define INSERT8(L, u)                                                          \
  {                                                                            \
    float n0 = __builtin_amdgcn_fmed3f(u, L[0], L[1]);                         \
    float n1 = __builtin_amdgcn_fmed3f(u, L[1], L[2]);                         \
    float n2 = __builtin_amdgcn_fmed3f(u, L[2], L[3]);                         \
    float n3 = __builtin_amdgcn_fmed3f(u, L[3], L[4]);                         \
    float n4 = __builtin_amdgcn_fmed3f(u, L[4], L[5]);                         \
    float n5 = __builtin_amdgcn_fmed3f(u, L[5], L[6]);                         \
    float n6 = __builtin_amdgcn_fmed3f(u, L[6], L[7]);                         \
    float n7 = fmaxf(L[7], u);                                                 \
    L[0] = n0; L[1] = n1; L[2] = n2; L[3] = n3;                                \
    L[4] = n4; L[5] = n5; L[6] = n6; L[7] = n7;                                \
  }

// --- K1: exact 8-NN. 4 queries/lane x 16-way M-split over candidate PAIRS;
//     packed-f32 dots/accumulates (v_pk_fma_f32); scalar med3 inserts. -------
__global__ __launch_bounds__(TPB, 4) void knn7_kernel(const float* __restrict__ partial,
                                                      const float* __restrict__ predicted,
                                                      float* __restrict__ outp) {
  __shared__ float4 pxy[Mm / 2];              // 16 KiB {x0,x1,y0,y1} per pair
  __shared__ float4 pzw[Mm / 2];              // 16 KiB {z0,z1,w0,w1}
  const int b  = blockIdx.x >> 7;             // 1024 blocks: 8 b x 128 qt
  const int qt = blockIdx.x & 127;
  const int tid = threadIdx.x;

  { // stage candidates 8t..8t+7 (pairs 4t..4t+3)
    const float4* pv = (const float4*)(partial + (size_t)b * Mm * 3) + 6 * tid;
    float4 v0 = pv[0], v1 = pv[1], v2 = pv[2], v3 = pv[3], v4 = pv[4], v5 = pv[5];
    float xs[8] = {v0.x, v0.w, v1.z, v2.y, v3.x, v3.w, v4.z, v5.y};
    float ys[8] = {v0.y, v1.x, v1.w, v2.z, v3.y, v4.x, v4.w, v5.z};
    float zs[8] = {v0.z, v1.y, v2.x, v2.w, v3.z, v4.y, v5.x, v5.w};
    #pragma unroll
    for (int j = 0; j < 4; ++j) {
      int p = 4 * tid + j;
      float x0 = xs[2*j], x1 = xs[2*j+1], y0 = ys[2*j], y1 = ys[2*j+1];
      float z0 = zs[2*j], z1 = zs[2*j+1];
      pxy[p] = make_float4(x0, x1, y0, y1);
      pzw[p] = make_float4(z0, z1,
                           -0.5f * fmaf(x0, x0, fmaf(y0, y0, z0 * z0)),
                           -0.5f * fmaf(x1, x1, fmaf(y1, y1, z1 * z1)));
    }
  }
  __syncthreads();

  const int lane = tid & 63, w = tid >> 6;
  const int s = lane & 15, g = lane >> 4;
  const int qbase = qt * 64 + w * 16 + g * 4;
  const float4* qp = (const float4*)(predicted + ((size_t)b * Nn + qbase) * 3);
  const float4 qa = qp[0], qb4 = qp[1], qc = qp[2];
  const float q0x = qa.x,  q0y = qa.y,  q0z = qa.z;
  const float q1x = qa.w,  q1y = qb4.x, q1z = qb4.y;
  const float q2x = qb4.z, q2y = qb4.w, q2z = qc.x;
  const float q3x = qc.y,  q3y = qc.z,  q3z = qc.w;
  // loop-invariant splat pairs (no per-iter dup movs)
  const f32x2 q0x2 = {q0x, q0x}, q0y2 = {q0y, q0y}, q0z2 = {q0z, q0z};
  const f32x2 q1x2 = {q1x, q1x}, q1y2 = {q1y, q1y}, q1z2 = {q1z, q1z};
  const f32x2 q2x2 = {q2x, q2x}, q2y2 = {q2y, q2y}, q2z2 = {q2z, q2z};
  const f32x2 q3x2 = {q3x, q3x}, q3y2 = {q3y, q3y}, q3z2 = {q3z, q3z};

  // pass A: per-query ascending top-8 over this lane's 64 pairs
  float l0[8], l1[8], l2[8], l3[8];
  #pragma unroll
  for (int i = 0; i < 8; ++i) { l0[i] = -INFINITY; l1[i] = -INFINITY;
                                l2[i] = -INFINITY; l3[i] = -INFINITY; }
  #pragma unroll 4
  for (int j = 0; j < 64; ++j) {
    int p = s + 16 * j;
    float4 axy = pxy[p], azw = pzw[p];
    f32x2 x01 = {axy.x, axy.y}, y01 = {axy.z, axy.w};
    f32x2 z01 = {azw.x, azw.y}, w01 = {azw.z, azw.w};
    f32x2 U0 = fma2(q0x2, x01, fma2(q0y2, y01, fma2(q0z2, z01, w01)));
    f32x2 U1 = fma2(q1x2, x01, fma2(q1y2, y01, fma2(q1z2, z01, w01)));
    f32x2 U2 = fma2(q2x2, x01, fma2(q2y2, y01, fma2(q2z2, z01, w01)));
    f32x2 U3 = fma2(q3x2, x01, fma2(q3y2, y01, fma2(q3z2, z01, w01)));
    INSERT8(l0, U0.x); INSERT8(l0, U0.y);
    INSERT8(l1, U1.x); INSERT8(l1, U1.y);
    INSERT8(l2, U2.x); INSERT8(l2, U2.y);
    INSERT8(l3, U3.x); INSERT8(l3, U3.y);
  }

  // merge 16 subset lists per query: full merges at d=1,2,4; t8-only at d=8
  #pragma unroll
  for (int dd = 0; dd < 3; ++dd) {
    const int d = 1 << dd;
    float ob[8];
    #pragma unroll
    for (int i = 0; i < 8; ++i) ob[i] = __shfl_xor(l0[i], d);
    mergeTop8(l0, ob);
    #pragma unroll
    for (int i = 0; i < 8; ++i) ob[i] = __shfl_xor(l1[i], d);
    mergeTop8(l1, ob);
    #pragma unroll
    for (int i = 0; i < 8; ++i) ob[i] = __shfl_xor(l2[i], d);
    mergeTop8(l2, ob);
    #pragma unroll
    for (int i = 0; i < 8; ++i) ob[i] = __shfl_xor(l3[i], d);
    mergeTop8(l3, ob);
  }
  float t80, t81, t82, t83;
  {
    float ob[8];
    #pragma unroll
    for (int i = 0; i < 8; ++i) ob[i] = __shfl_xor(l0[i], 8);
    t80 = t8of(l0, ob);
    #pragma unroll
    for (int i = 0; i < 8; ++i) ob[i] = __shfl_xor(l1[i], 8);
    t81 = t8of(l1, ob);
    #pragma unroll
    for (int i = 0; i < 8; ++i) ob[i] = __shfl_xor(l2[i], 8);
    t82 = t8of(l2, ob);
    #pragma unroll
    for (int i = 0; i < 8; ++i) ob[i] = __shfl_xor(l3[i], 8);
    t83 = t8of(l3, ob);
  }

  // pass B: packed accumulate of winners (u >= t8)
  f32x2 ax0 = {0.f, 0.f}, ay0 = ax0, az0 = ax0, ac0 = ax0;
  f32x2 ax1 = ax0, ay1 = ax0, az1 = ax0, ac1 = ax0;
  f32x2 ax2 = ax0, ay2 = ax0, az2 = ax0, ac2 = ax0;
  f32x2 ax3 = ax0, ay3 = ax0, az3 = ax0, ac3 = ax0;
  #pragma unroll 4
  for (int j = 0; j < 64; ++j) {
    int p = s + 16 * j;
    float4 axy = pxy[p], azw = pzw[p];
    f32x2 x01 = {axy.x, axy.y}, y01 = {axy.z, axy.w};
    f32x2 z01 = {azw.x, azw.y}, w01 = {azw.z, azw.w};
    f32x2 U0 = fma2(q0x2, x01, fma2(q0y2, y01, fma2(q0z2, z01, w01)));  // bitwise
    f32x2 U1 = fma2(q1x2, x01, fma2(q1y2, y01, fma2(q1z2, z01, w01)));  //  same
    f32x2 U2 = fma2(q2x2, x01, fma2(q2y2, y01, fma2(q2z2, z01, w01)));  //  as A
    f32x2 U3 = fma2(q3x2, x01, fma2(q3y2, y01, fma2(q3z2, z01, w01)));
    f32x2 m0 = {U0.x >= t80 ? 1.f : 0.f, U0.y >= t80 ? 1.f : 0.f};
    f32x2 m1 = {U1.x >= t81 ? 1.f : 0.f, U1.y >= t81 ? 1.f : 0.f};
    f32x2 m2 = {U2.x >= t82 ? 1.f : 0.f, U2.y >= t82 ? 1.f : 0.f};
    f32x2 m3 = {U3.x >= t83 ? 1.f : 0.f, U3.y >= t83 ? 1.f : 0.f};
    ax0 = fma2(m0, x01, ax0); ay0 = fma2(m0, y01, ay0); az0 = fma2(m0, z01, az0); ac0 += m0;
    ax1 = fma2(m1, x01, ax1); ay1 = fma2(m1, y01, ay1); az1 = fma2(m1, z01, az1); ac1 += m1;
    ax2 = fma2(m2, x01, ax2); ay2 = fma2(m2, y01, ay2); az2 = fma2(m2, z01, az2); ac2 += m2;
    ax3 = fma2(m3, x01, ax3); ay3 = fma2(m3, y01, ay3); az3 = fma2(m3, z01, az3); ac3 += m3;
  }
  float sx0 = ax0.x + ax0.y, sy0 = ay0.x + ay0.y, sz0 = az0.x + az0.y, c0 = ac0.x + ac0.y;
  float sx1 = ax1.x + ax1.y, sy1 = ay1.x + ay1.y, sz1 = az1.x + az1.y, c1 = ac1.x + ac1.y;
  float sx2 = ax2.x + ax2.y, sy2 = ay2.x + ay2.y, sz2 = az2.x + az2.y, c2 = ac2.x + ac2.y;
  float sx3 = ax3.x + ax3.y, sy3 = ay3.x + ay3.y, sz3 = az3.x + az3.y, c3 = ac3.x + ac3.y;
  #pragma unroll
  for (int dd = 0; dd < 4; ++dd) {
    const int d = 1 << dd;
    sx0 += __shfl_xor(sx0, d); sy0 += __shfl_xor(sy0, d); sz0 += __shfl_xor(sz0, d); c0 += __shfl_xor(c0, d);
    sx1 += __shfl_xor(sx1, d); sy1 += __shfl_xor(sy1, d); sz1 += __shfl_xor(sz1, d); c1 += __shfl_xor(c1, d);
    sx2 += __shfl_xor(sx2, d); sy2 += __shfl_xor(sy2, d); sz2 += __shfl_xor(sz2, d); c2 += __shfl_xor(c2, d);
    sx3 += __shfl_xor(sx3, d); sy3 += __shfl_xor(sy3, d); sz3 += __shfl_xor(sz3, d); c3 += __shfl_xor(c3, d);
  }

  #pragma unroll
  for (int k = 0; k < 4; ++k) {
    if (s == k) {
      float qx = (k == 0) ? q0x : (k == 1) ? q1x : (k == 2) ? q2x : q3x;
      float qy = (k == 0) ? q0y : (k == 1) ? q1y : (k == 2) ? q2y : q3y;
      float qz = (k == 0) ? q0z : (k == 1) ? q1z : (k == 2) ? q2z : q3z;
      float t8 = (k == 0) ? t80 : (k == 1) ? t81 : (k == 2) ? t82 : t83;
      float sx = (k == 0) ? sx0 : (k == 1) ? sx1 : (k == 2) ? sx2 : sx3;
      float sy = (k == 0) ? sy0 : (k == 1) ? sy1 : (k == 2) ? sy2 : sy3;
      float sz = (k == 0) ? sz0 : (k == 1) ? sz1 : (k == 2) ? sz2 : sz3;
      float cn = (k == 0) ? c0  : (k == 1) ? c1  : (k == 2) ? c2  : c3;
      if (cn != 8.0f) {                       // duplicate boundary ties: rare
        sx = sy = sz = 0.f; float cw = 0.f;
        for (int m = 0; m < Mm; ++m) {        // strict winners
          float4 a = pxy[m >> 1], c4 = pzw[m >> 1];
          int o = m & 1;
          float px = o ? a.y : a.x, py = o ? a.w : a.z;
          float pz = o ? c4.y : c4.x, pw = o ? c4.w : c4.z;
          float u = fmaf(qx, px, fmaf(qy, py, fmaf(qz, pz, pw)));
          if (u > t8) { sx += px; sy += py; sz += pz; cw += 1.f; }
        }
        int need = 8 - (int)cw, got = 0;
        for (int m = 0; m < Mm && got < need; ++m) {   // earliest == ties
          float4 a = pxy[m >> 1], c4 = pzw[m >> 1];
          int o = m & 1;
          float px = o ? a.y : a.x, py = o ? a.w : a.z;
          float pz = o ? c4.y : c4.x, pw = o ? c4.w : c4.z;
          float u = fmaf(qx, px, fmaf(qy, py, fmaf(qz, pz, pw)));
          if (u == t8) { sx += px; sy += py; sz += pz; ++got; }
        }
      }
      float2* co = (float2*)(outp + ((size_t)b * Nn + qbase + k) * 6);
      co[0] = make_float2(qx, qy);
      co[1] = make_float2(qz, sx * 0.125f);
      co[2] = make_float2(sy * 0.125f, sz * 0.125f);
    }
  }
}

// --- K2: fc1(regs) -> A to LDS(bf16,swizzled) -> MFMA GEMM vs Bpack -> epilogue
__global__ __launch_bounds__(TPB) void mlp_mfma(const float* __restrict__ W1,
    const float* __restrict__ b1, const unsigned short* __restrict__ Bpack,
    const float* __restrict__ Cf, const float* __restrict__ Wc,
    const float* __restrict__ bc, float* __restrict__ outp) {
  extern __shared__ char Alds[];              // 65536 B: A[256 rows][128 k] bf16
  const int tid = threadIdx.x;
  const int row0 = blockIdx.x * TPB;
  const int vz = vzero();

  { // phase 1: fc1 + relu for row = row0 + tid; stage bf16 row to LDS
    const float* rp = outp + (size_t)(row0 + tid) * 6;
    float2 r0 = *(const float2*)rp, r1 = *(const float2*)(rp + 2),
           r2 = *(const float2*)(rp + 4);
    const float c0 = r0.x, c1 = r0.y, c2 = r1.x, c3 = r1.y, c4 = r2.x, c5 = r2.y;
    float4 h4[32];
    #pragma unroll
    for (int j4 = 0; j4 < 32; ++j4) {
      float4 bb = ((const float4*)b1)[j4];
      float4 w0 = ldg4(W1, j4 * 6 + 0, vz), w1 = ldg4(W1, j4 * 6 + 1, vz),
             w2 = ldg4(W1, j4 * 6 + 2, vz), w3 = ldg4(W1, j4 * 6 + 3, vz),
             w4 = ldg4(W1, j4 * 6 + 4, vz), w5 = ldg4(W1, j4 * 6 + 5, vz);
      float a0 = bb.x, a1 = bb.y, a2 = bb.z, a3 = bb.w;
      a0 = fmaf(c0, w0.x, a0); a0 = fmaf(c1, w0.y, a0); a0 = fmaf(c2, w0.z, a0);
      a0 = fmaf(c3, w0.w, a0); a0 = fmaf(c4, w1.x, a0); a0 = fmaf(c5, w1.y, a0);
      a1 = fmaf(c0, w1.z, a1); a1 = fmaf(c1, w1.w, a1); a1 = fmaf(c2, w2.x, a1);
      a1 = fmaf(c3, w2.y, a1); a1 = fmaf(c4, w2.z, a1); a1 = fmaf(c5, w2.w, a1);
      a2 = fmaf(c0, w3.x, a2); a2 = fmaf(c1, w3.y, a2); a2 = fmaf(c2, w3.z, a2);
      a2 = fmaf(c3, w3.w, a2); a2 = fmaf(c4, w4.x, a2); a2 = fmaf(c5, w4.y, a2);
      a3 = fmaf(c0, w4.z, a3); a3 = fmaf(c1, w4.w, a3); a3 = fmaf(c2, w5.x, a3);
      a3 = fmaf(c3, w5.y, a3); a3 = fmaf(c4, w5.z, a3); a3 = fmaf(c5, w5.w, a3);
      h4[j4] = make_float4(fmaxf(a0, 0.f), fmaxf(a1, 0.f), fmaxf(a2, 0.f), fmaxf(a3, 0.f));
    }
    #pragma unroll
    for (int c = 0; c < 16; ++c) {            // 16 B chunks, XOR-swizzled
      float4 lo = h4[c * 2], hi = h4[c * 2 + 1];
      union { unsigned short us[8]; uint4 v; } pk;
      pk.us[0] = f2b(lo.x); pk.us[1] = f2b(lo.y); pk.us[2] = f2b(lo.z); pk.us[3] = f2b(lo.w);
      pk.us[4] = f2b(hi.x); pk.us[5] = f2b(hi.y); pk.us[6] = f2b(hi.z); pk.us[7] = f2b(hi.w);
      int byte = tid * 256 + ((c * 16) ^ ((tid & 7) << 4));
      *(uint4*)(Alds + byte) = pk.v;
    }
  }
  __syncthreads();

  // phase 2: wave computes rows [row0+wid*64, +64) x 256 cols via MFMA
  const int lane = tid & 63, wid = tid >> 6;
  const int g = lane >> 4, cidx = lane & 15;
  float ac[4][4][3] = {};

  for (int chunk = 0; chunk < 4; ++chunk) {
    f32x4 acc[4][4];
    #pragma unroll
    for (int n = 0; n < 4; ++n) {
      float cfv = Cf[chunk * 64 + n * 16 + cidx];
      #pragma unroll
      for (int m = 0; m < 4; ++m) acc[m][n] = (f32x4){cfv, cfv, cfv, cfv};
    }
    #pragma unroll
    for (int ks = 0; ks < 4; ++ks) {
      short8 af[4];
      #pragma unroll
      for (int m = 0; m < 4; ++m) {
        int r = wid * 64 + m * 16 + cidx;
        int byte = r * 256 + ((ks * 64 + g * 16) ^ ((r & 7) << 4));
        af[m] = *(const short8*)(Alds + byte);
      }
      short8 bf[4];
      #pragma unroll
      for (int n = 0; n < 4; ++n)
        bf[n] = *(const short8*)((const char*)Bpack +
                 (((chunk * 4 + ks) * 4 + n) * 1024) + lane * 16);
      #pragma unroll
      for (int m = 0; m < 4; ++m)
        #pragma unroll
        for (int n = 0; n < 4; ++n)
          acc[m][n] = __builtin_amdgcn_mfma_f32_16x16x32_bf16(af[m], bf[n], acc[m][n], 0, 0, 0);
    }
    #pragma unroll
    for (int n = 0; n < 4; ++n) {
      int ot = chunk * 64 + n * 16 + cidx;
      int o = ot >> 1;
      float wc0 = Wc[o], wc1 = Wc[HID + o], wc2 = Wc[2 * HID + o];
      #pragma unroll
      for (int m = 0; m < 4; ++m) {
        #pragma unroll
        for (int i = 0; i < 4; ++i) {
          float v = fmaxf(acc[m][n][i], 0.f);
          ac[m][i][0] = fmaf(v, wc0, ac[m][i][0]);
          ac[m][i][1] = fmaf(v, wc1, ac[m][i][1]);
          ac[m][i][2] = fmaf(v, wc2, ac[m][i][2]);
        }
      }
    }
  }

  const float bc0 = bc[0], bc1 = bc[1], bc2 = bc[2];
  #pragma unroll
  for (int m = 0; m < 4; ++m) {
    #pragma unroll
    for (int i = 0; i < 4; ++i) {
      float s0 = ac[m][i][0], s1 = ac[m][i][1], s2 = ac[m][i][2];
      s0 += __shfl_xor(s0, 2); s0 += __shfl_xor(s0, 4); s0 += __shfl_xor(s0, 8);
      s1 += __shfl_xor(s1, 2); s1 += __shfl_xor(s1, 4); s1 += __shfl_xor(s1, 8);
      s2 += __shfl_xor(s2, 2); s2 += __shfl_xor(s2, 4); s2 += __shfl_xor(s2, 8);
      float o0 = __shfl_xor(s0, 1), o1 = __shfl_xor(s1, 1), o2 = __shfl_xor(s2, 1);
      const bool odd = lane & 1;
      float t00 = odd ? o0 : s0, t01 = odd ? o1 : s1, t02 = odd ? o2 : s2;
      float t10 = odd ? s0 : o0, t11 = odd ? s1 : o1, t12 = odd ? s2 : o2;
      if (cidx == m * 4 + i) {
        int row = row0 + wid * 64 + m * 16 + g * 4 + i;
        float* rp = outp + (size_t)row * 6;
        float px = rp[0], py = rp[1], pz = rp[2];
        rp[0] = px + t00 + bc0; rp[1] = py + t01 + bc1; rp[2] = pz + t02 + bc2;
        rp[3] = px + t10 + bc0; rp[4] = py + t11 + bc1; rp[5] = pz + t12 + bc2;
      }
    }
  }
}

// --- correctness-only fallback if ws too small (no ws use) ------------------
__global__ __launch_bounds__(TPB) void mlp_fallback(
    const float* __restrict__ W1, const float* __restrict__ b1,
    const float* __restrict__ W2, const float* __restrict__ b2,
    const float* __restrict__ Wd, const float* __restrict__ bd,
    const float* __restrict__ Wc, const float* __restrict__ bc,
    float* __restrict__ outp) {
  const int row = blockIdx.x * TPB + threadIdx.x;
  float2* rp = (float2*)(outp + (size_t)row * 6);
  float2 r0 = rp[0], r1 = rp[1], r2 = rp[2];
  float cc[6] = {r0.x, r0.y, r1.x, r1.y, r2.x, r2.y};
  float h[HID];
  for (int j = 0; j < HID; ++j) {
    float a = b1[j];
    for (int c = 0; c < 6; ++c) a = fmaf(cc[c], W1[j * 6 + c], a);
    h[j] = fmaxf(a, 0.f);
  }
  float sd[HID];
  for (int i = 0; i < HID; ++i) {
    float a = b2[i];
    for (int j = 0; j < HID; ++j) a = fmaf(h[j], W2[i * HID + j], a);
    sd[i] = a;
  }
  float ov[3][2] = {};
  for (int oc = 0; oc < HID; ++oc)
    for (int t = 0; t < 2; ++t) {
      float a = bd[oc];
      for (int i = 0; i < HID; ++i) a = fmaf(sd[i], Wd[i * 256 + oc * 2 + t], a);
      a = fmaxf(a, 0.f);
      for (int c = 0; c < 3; ++c) ov[c][t] = fmaf(a, Wc[c * HID + oc], ov[c][t]);
    }
  rp[0] = make_float2(cc[0] + ov[0][0] + bc[0], cc[1] + ov[1][0] + bc[1]);
  rp[1] = make_float2(cc[2] + ov[2][0] + bc[2], cc[0] + ov[0][1] + bc[0]);
  rp[2] = make_float2(cc[1] + ov[1][1] + bc[1], cc[2] + ov[2][1] + bc[2]);
}

extern "C" void kernel_launch(void* const* d_in, const int* in_sizes, int n_in,
                              void* d_out, int out_size, void* d_ws, size_t ws_size,
                              hipStream_t stream) {
  const float* partial   = (const float*)d_in[0];
  const float* predicted = (const float*)d_in[1];
  const float* W1 = (const float*)d_in[2];
  const float* b1 = (const float*)d_in[3];
  const float* W2 = (const float*)d_in[4];
  const float* b2 = (const float*)d_in[5];
  const float* Wd = (const float*)d_in[6];
  const float* bd = (const float*)d_in[7];
  const float* Wc = (const float*)d_in[8];
  const float* bc = (const float*)d_in[9];
  float* outp = (float*)d_out;

  unsigned short* Bpack = (unsigned short*)d_ws;       // 65536 B
  float* Cf = (float*)((char*)d_ws + 65536);           // 1024 B
  const bool fits = ws_size >= (size_t)66560;

  if (fits)
    hipLaunchKernelGGL(prep2_kernel, dim3(128), dim3(TPB), 0, stream,
                       W2, b2, Wd, bd, Bpack, Cf);
  hipLaunchKernelGGL(knn7_kernel, dim3(Bb * 128), dim3(TPB), 0, stream,
                     partial, predicted, outp);
  if (fits)
    hipLaunchKernelGGL(mlp_mfma, dim3((Bb * Nn) / TPB), dim3(TPB), 65536, stream,
                       W1, b1, Bpack, Cf, Wc, bc, outp);
  else
    hipLaunchKernelGGL(mlp_fallback, dim3((Bb * Nn) / TPB), dim3(TPB), 0, stream,
                       W1, b1, W2, b2, Wd, bd, Wc, bc, outp);
}

// Round 9
// 98.964 us; speedup vs baseline: 1.0030x; 1.0030x over previous
//
#include <hip/hip_runtime.h>
#include <hip/hip_bf16.h>
#include <math.h>

#define TPB 256
constexpr int Bb = 8, Mm = 2048, Nn = 8192, HID = 128;

typedef __attribute__((ext_vector_type(8))) short short8;
typedef __attribute__((ext_vector_type(4))) float f32x4;
typedef __attribute__((ext_vector_type(2))) float f32x2;

__device__ __forceinline__ int vzero() { int v; asm("v_mov_b32 %0, 0" : "=v"(v)); return v; }
__device__ __forceinline__ float4 ldg4(const float* __restrict__ p, int idx4, int vz) {
  return ((const float4*)p)[idx4 + vz];
}
__device__ __forceinline__ unsigned short f2b(float x) {
  __hip_bfloat16 h = __float2bfloat16(x);
  return *reinterpret_cast<unsigned short*>(&h);
}
__device__ __forceinline__ f32x2 fma2(f32x2 a, f32x2 b, f32x2 c) {
  return __builtin_elementwise_fma(a, b, c);      // -> v_pk_fma_f32
}

// --- K0: pack fused weights Wf = W2^T·Wd into MFMA-B fragment order (bf16) ---
__global__ __launch_bounds__(TPB) void prep2_kernel(const float* __restrict__ W2,
    const float* __restrict__ b2, const float* __restrict__ Wd,
    const float* __restrict__ bd, unsigned short* __restrict__ Bpack,
    float* __restrict__ Cf) {
  int idx = blockIdx.x * TPB + threadIdx.x;   // 0..32767
  int f = idx >> 9, r = idx & 511, lane = r >> 3, j = r & 7;
  int chunk = f >> 4, ks = (f >> 2) & 3, n = f & 3;
  int k   = ks * 32 + (lane >> 4) * 8 + j;
  int col = chunk * 64 + n * 16 + (lane & 15);
  float acc = 0.f;
  for (int i = 0; i < HID; ++i)
    acc = fmaf(W2[i * HID + k], Wd[i * 256 + col], acc);
  Bpack[idx] = f2b(acc);
  if (idx < 256) {
    float c = bd[idx >> 1];
    for (int i = 0; i < HID; ++i) c = fmaf(b2[i], Wd[i * 256 + idx], c);
    Cf[idx] = c;
  }
}

// in-place: a = sorted-asc top-8 of union(a,b); a,b sorted-asc top-8 lists
__device__ __forceinline__ void mergeTop8(float a[8], const float b[8]) {
  float w[8];
  #pragma unroll
  for (int i = 0; i < 8; ++i) w[i] = fmaxf(a[i], b[7 - i]);
  #pragma unroll
  for (int i = 0; i < 4; ++i) {
    float lo = fminf(w[i], w[i + 4]); w[i + 4] = fmaxf(w[i], w[i + 4]); w[i] = lo;
  }
  #pragma unroll
  for (int g = 0; g < 8; g += 4)
    #pragma unroll
    for (int i = 0; i < 2; ++i) {
      float lo = fminf(w[g + i], w[g + i + 2]);
      w[g + i + 2] = fmaxf(w[g + i], w[g + i + 2]); w[g + i] = lo;
    }
  #pragma unroll
  for (int i = 0; i < 8; i += 2) {
    float lo = fminf(w[i], w[i + 1]); w[i + 1] = fmaxf(w[i], w[i + 1]); w[i] = lo;
  }
  #pragma unroll
  for (int i = 0; i < 8; ++i) a[i] = w[i];
}
__device__ __forceinline__ float t8of(const float a[8], const float b[8]) {
  float t = fmaxf(a[0], b[7]);
  #pragma unroll
  for (int i = 1; i < 8; ++i) t = fminf(t, fmaxf(a[i], b[7 - i]));
  return t;
}

// In-place ascending insert: step i reads only not-yet-overwritten slots.
#define INSERT8(L, u)                                                          \
  {                                                                            \
    L[0] = __builtin_amdgcn_fmed3f(u, L[0], L[1]);                             \
    L[1] = __builtin_amdgcn_fmed3f(u, L[1], L[2]);                             \
    L[2] = __builtin_amdgcn_fmed3f(u, L[2], L[3]);                             \
    L[3] = __builtin_amdgcn_fmed3f(u, L[3], L[4]);                             \
    L[4] = __builtin_amdgcn_fmed3f(u, L[4], L[5]);                             \
    L[5] = __builtin_amdgcn_fmed3f(u, L[5], L[6]);                             \
    L[6] = __builtin_amdgcn_fmed3f(u, L[6], L[7]);                             \
    L[7] = fmaxf(L[7], u);                                                     \
  }

// --- K1: exact 8-NN. 4 queries/lane x 16-way M-split over candidate PAIRS;
//     packed-f32 dots/accumulates; unroll-8 for LDS latency hiding. ----------
__global__ __launch_bounds__(TPB, 4) void knn8_kernel(const float* __restrict__ partial,
                                                      const float* __restrict__ predicted,
                                                      float* __restrict__ outp) {
  __shared__ float4 pxy[Mm / 2];              // 16 KiB {x0,x1,y0,y1} per pair
  __shared__ float4 pzw[Mm / 2];              // 16 KiB {z0,z1,w0,w1}
  const int b  = blockIdx.x >> 7;             // 1024 blocks: 8 b x 128 qt
  const int qt = blockIdx.x & 127;
  const int tid = threadIdx.x;

  { // stage candidates 8t..8t+7 (pairs 4t..4t+3)
    const float4* pv = (const float4*)(partial + (size_t)b * Mm * 3) + 6 * tid;
    float4 v0 = pv[0], v1 = pv[1], v2 = pv[2], v3 = pv[3], v4 = pv[4], v5 = pv[5];
    float xs[8] = {v0.x, v0.w, v1.z, v2.y, v3.x, v3.w, v4.z, v5.y};
    float ys[8] = {v0.y, v1.x, v1.w, v2.z, v3.y, v4.x, v4.w, v5.z};
    float zs[8] = {v0.z, v1.y, v2.x, v2.w, v3.z, v4.y, v5.x, v5.w};
    #pragma unroll
    for (int j = 0; j < 4; ++j) {
      int p = 4 * tid + j;
      float x0 = xs[2*j], x1 = xs[2*j+1], y0 = ys[2*j], y1 = ys[2*j+1];
      float z0 = zs[2*j], z1 = zs[2*j+1];
      pxy[p] = make_float4(x0, x1, y0, y1);
      pzw[p] = make_float4(z0, z1,
                           -0.5f * fmaf(x0, x0, fmaf(y0, y0, z0 * z0)),
                           -0.5f * fmaf(x1, x1, fmaf(y1, y1, z1 * z1)));
    }
  }
  __syncthreads();

  const int lane = tid & 63, w = tid >> 6;
  const int s = lane & 15, g = lane >> 4;
  const int qbase = qt * 64 + w * 16 + g * 4;
  const float4* qp = (const float4*)(predicted + ((size_t)b * Nn + qbase) * 3);
  const float4 qa = qp[0], qb4 = qp[1], qc = qp[2];
  const float q0x = qa.x,  q0y = qa.y,  q0z = qa.z;
  const float q1x = qa.w,  q1y = qb4.x, q1z = qb4.y;
  const float q2x = qb4.z, q2y = qb4.w, q2z = qc.x;
  const float q3x = qc.y,  q3y = qc.z,  q3z = qc.w;
  const f32x2 q0x2 = {q0x, q0x}, q0y2 = {q0y, q0y}, q0z2 = {q0z, q0z};
  const f32x2 q1x2 = {q1x, q1x}, q1y2 = {q1y, q1y}, q1z2 = {q1z, q1z};
  const f32x2 q2x2 = {q2x, q2x}, q2y2 = {q2y, q2y}, q2z2 = {q2z, q2z};
  const f32x2 q3x2 = {q3x, q3x}, q3y2 = {q3y, q3y}, q3z2 = {q3z, q3z};

  // pass A: per-query ascending top-8 over this lane's 64 pairs
  float l0[8], l1[8], l2[8], l3[8];
  #pragma unroll
  for (int i = 0; i < 8; ++i) { l0[i] = -INFINITY; l1[i] = -INFINITY;
                                l2[i] = -INFINITY; l3[i] = -INFINITY; }
  #pragma unroll 8
  for (int j = 0; j < 64; ++j) {
    int p = s + 16 * j;
    float4 axy = pxy[p], azw = pzw[p];
    f32x2 x01 = {axy.x, axy.y}, y01 = {axy.z, axy.w};
    f32x2 z01 = {azw.x, azw.y}, w01 = {azw.z, azw.w};
    f32x2 U0 = fma2(q0x2, x01, fma2(q0y2, y01, fma2(q0z2, z01, w01)));
    f32x2 U1 = fma2(q1x2, x01, fma2(q1y2, y01, fma2(q1z2, z01, w01)));
    f32x2 U2 = fma2(q2x2, x01, fma2(q2y2, y01, fma2(q2z2, z01, w01)));
    f32x2 U3 = fma2(q3x2, x01, fma2(q3y2, y01, fma2(q3z2, z01, w01)));
    INSERT8(l0, U0.x); INSERT8(l0, U0.y);
    INSERT8(l1, U1.x); INSERT8(l1, U1.y);
    INSERT8(l2, U2.x); INSERT8(l2, U2.y);
    INSERT8(l3, U3.x); INSERT8(l3, U3.y);
  }

  // merge 16 subset lists per query: full merges at d=1,2,4; t8-only at d=8
  #pragma unroll
  for (int dd = 0; dd < 3; ++dd) {
    const int d = 1 << dd;
    float ob[8];
    #pragma unroll
    for (int i = 0; i < 8; ++i) ob[i] = __shfl_xor(l0[i], d);
    mergeTop8(l0, ob);
    #pragma unroll
    for (int i = 0; i < 8; ++i) ob[i] = __shfl_xor(l1[i], d);
    mergeTop8(l1, ob);
    #pragma unroll
    for (int i = 0; i < 8; ++i) ob[i] = __shfl_xor(l2[i], d);
    mergeTop8(l2, ob);
    #pragma unroll
    for (int i = 0; i < 8; ++i) ob[i] = __shfl_xor(l3[i], d);
    mergeTop8(l3, ob);
  }
  float t80, t81, t82, t83;
  {
    float ob[8];
    #pragma unroll
    for (int i = 0; i < 8; ++i) ob[i] = __shfl_xor(l0[i], 8);
    t80 = t8of(l0, ob);
    #pragma unroll
    for (int i = 0; i < 8; ++i) ob[i] = __shfl_xor(l1[i], 8);
    t81 = t8of(l1, ob);
    #pragma unroll
    for (int i = 0; i < 8; ++i) ob[i] = __shfl_xor(l2[i], 8);
    t82 = t8of(l2, ob);
    #pragma unroll
    for (int i = 0; i < 8; ++i) ob[i] = __shfl_xor(l3[i], 8);
    t83 = t8of(l3, ob);
  }

  // pass B: packed accumulate of winners (u >= t8)
  f32x2 ax0 = {0.f, 0.f}, ay0 = ax0, az0 = ax0, ac0 = ax0;
  f32x2 ax1 = ax0, ay1 = ax0, az1 = ax0, ac1 = ax0;
  f32x2 ax2 = ax0, ay2 = ax0, az2 = ax0, ac2 = ax0;
  f32x2 ax3 = ax0, ay3 = ax0, az3 = ax0, ac3 = ax0;
  #pragma unroll 8
  for (int j = 0; j < 64; ++j) {
    int p = s + 16 * j;
    float4 axy = pxy[p], azw = pzw[p];
    f32x2 x01 = {axy.x, axy.y}, y01 = {axy.z, axy.w};
    f32x2 z01 = {azw.x, azw.y}, w01 = {azw.z, azw.w};
    f32x2 U0 = fma2(q0x2, x01, fma2(q0y2, y01, fma2(q0z2, z01, w01)));  // bitwise
    f32x2 U1 = fma2(q1x2, x01, fma2(q1y2, y01, fma2(q1z2, z01, w01)));  //  same
    f32x2 U2 = fma2(q2x2, x01, fma2(q2y2, y01, fma2(q2z2, z01, w01)));  //  as A
    f32x2 U3 = fma2(q3x2, x01, fma2(q3y2, y01, fma2(q3z2, z01, w01)));
    f32x2 m0 = {U0.x >= t80 ? 1.f : 0.f, U0.y >= t80 ? 1.f : 0.f};
    f32x2 m1 = {U1.x >= t81 ? 1.f : 0.f, U1.y >= t81 ? 1.f : 0.f};
    f32x2 m2 = {U2.x >= t82 ? 1.f : 0.f, U2.y >= t82 ? 1.f : 0.f};
    f32x2 m3 = {U3.x >= t83 ? 1.f : 0.f, U3.y >= t83 ? 1.f : 0.f};
    ax0 = fma2(m0, x01, ax0); ay0 = fma2(m0, y01, ay0); az0 = fma2(m0, z01, az0); ac0 += m0;
    ax1 = fma2(m1, x01, ax1); ay1 = fma2(m1, y01, ay1); az1 = fma2(m1, z01, az1); ac1 += m1;
    ax2 = fma2(m2, x01, ax2); ay2 = fma2(m2, y01, ay2); az2 = fma2(m2, z01, az2); ac2 += m2;
    ax3 = fma2(m3, x01, ax3); ay3 = fma2(m3, y01, ay3); az3 = fma2(m3, z01, az3); ac3 += m3;
  }
  float sx0 = ax0.x + ax0.y, sy0 = ay0.x + ay0.y, sz0 = az0.x + az0.y, c0 = ac0.x + ac0.y;
  float sx1 = ax1.x + ax1.y, sy1 = ay1.x + ay1.y, sz1 = az1.x + az1.y, c1 = ac1.x + ac1.y;
  float sx2 = ax2.x + ax2.y, sy2 = ay2.x + ay2.y, sz2 = az2.x + az2.y, c2 = ac2.x + ac2.y;
  float sx3 = ax3.x + ax3.y, sy3 = ay3.x + ay3.y, sz3 = az3.x + az3.y, c3 = ac3.x + ac3.y;
  #pragma unroll
  for (int dd = 0; dd < 4; ++dd) {
    const int d = 1 << dd;
    sx0 += __shfl_xor(sx0, d); sy0 += __shfl_xor(sy0, d); sz0 += __shfl_xor(sz0, d); c0 += __shfl_xor(c0, d);
    sx1 += __shfl_xor(sx1, d); sy1 += __shfl_xor(sy1, d); sz1 += __shfl_xor(sz1, d); c1 += __shfl_xor(c1, d);
    sx2 += __shfl_xor(sx2, d); sy2 += __shfl_xor(sy2, d); sz2 += __shfl_xor(sz2, d); c2 += __shfl_xor(c2, d);
    sx3 += __shfl_xor(sx3, d); sy3 += __shfl_xor(sy3, d); sz3 += __shfl_xor(sz3, d); c3 += __shfl_xor(c3, d);
  }

  #pragma unroll
  for (int k = 0; k < 4; ++k) {
    if (s == k) {
      float qx = (k == 0) ? q0x : (k == 1) ? q1x : (k == 2) ? q2x : q3x;
      float qy = (k == 0) ? q0y : (k == 1) ? q1y : (k == 2) ? q2y : q3y;
      float qz = (k == 0) ? q0z : (k == 1) ? q1z : (k == 2) ? q2z : q3z;
      float t8 = (k == 0) ? t80 : (k == 1) ? t81 : (k == 2) ? t82 : t83;
      float sx = (k == 0) ? sx0 : (k == 1) ? sx1 : (k == 2) ? sx2 : sx3;
      float sy = (k == 0) ? sy0 : (k == 1) ? sy1 : (k == 2) ? sy2 : sy3;
      float sz = (k == 0) ? sz0 : (k == 1) ? sz1 : (k == 2) ? sz2 : sz3;
      float cn = (k == 0) ? c0  : (k == 1) ? c1  : (k == 2) ? c2  : c3;
      if (cn != 8.0f) {                       // duplicate boundary ties: rare
        sx = sy = sz = 0.f; float cw = 0.f;
        for (int m = 0; m < Mm; ++m) {        // strict winners
          float4 a = pxy[m >> 1], c4 = pzw[m >> 1];
          int o = m & 1;
          float px = o ? a.y : a.x, py = o ? a.w : a.z;
          float pz = o ? c4.y : c4.x, pw = o ? c4.w : c4.z;
          float u = fmaf(qx, px, fmaf(qy, py, fmaf(qz, pz, pw)));
          if (u > t8) { sx += px; sy += py; sz += pz; cw += 1.f; }
        }
        int need = 8 - (int)cw, got = 0;
        for (int m = 0; m < Mm && got < need; ++m) {   // earliest == ties
          float4 a = pxy[m >> 1], c4 = pzw[m >> 1];
          int o = m & 1;
          float px = o ? a.y : a.x, py = o ? a.w : a.z;
          float pz = o ? c4.y : c4.x, pw = o ? c4.w : c4.z;
          float u = fmaf(qx, px, fmaf(qy, py, fmaf(qz, pz, pw)));
          if (u == t8) { sx += px; sy += py; sz += pz; ++got; }
        }
      }
      float2* co = (float2*)(outp + ((size_t)b * Nn + qbase + k) * 6);
      co[0] = make_float2(qx, qy);
      co[1] = make_float2(qz, sx * 0.125f);
      co[2] = make_float2(sy * 0.125f, sz * 0.125f);
    }
  }
}

// --- K2: fc1(regs) -> A to LDS(bf16,swizzled) -> MFMA GEMM vs Bpack -> epilogue
__global__ __launch_bounds__(TPB) void mlp_mfma(const float* __restrict__ W1,
    const float* __restrict__ b1, const unsigned short* __restrict__ Bpack,
    const float* __restrict__ Cf, const float* __restrict__ Wc,
    const float* __restrict__ bc, float* __restrict__ outp) {
  extern __shared__ char Alds[];              // 65536 B: A[256 rows][128 k] bf16
  const int tid = threadIdx.x;
  const int row0 = blockIdx.x * TPB;
  const int vz = vzero();

  { // phase 1: fc1 + relu for row = row0 + tid; stage bf16 row to LDS
    const float* rp = outp + (size_t)(row0 + tid) * 6;
    float2 r0 = *(const float2*)rp, r1 = *(const float2*)(rp + 2),
           r2 = *(const float2*)(rp + 4);
    const float c0 = r0.x, c1 = r0.y, c2 = r1.x, c3 = r1.y, c4 = r2.x, c5 = r2.y;
    float4 h4[32];
    #pragma unroll
    for (int j4 = 0; j4 < 32; ++j4) {
      float4 bb = ((const float4*)b1)[j4];
      float4 w0 = ldg4(W1, j4 * 6 + 0, vz), w1 = ldg4(W1, j4 * 6 + 1, vz),
             w2 = ldg4(W1, j4 * 6 + 2, vz), w3 = ldg4(W1, j4 * 6 + 3, vz),
             w4 = ldg4(W1, j4 * 6 + 4, vz), w5 = ldg4(W1, j4 * 6 + 5, vz);
      float a0 = bb.x, a1 = bb.y, a2 = bb.z, a3 = bb.w;
      a0 = fmaf(c0, w0.x, a0); a0 = fmaf(c1, w0.y, a0); a0 = fmaf(c2, w0.z, a0);
      a0 = fmaf(c3, w0.w, a0); a0 = fmaf(c4, w1.x, a0); a0 = fmaf(c5, w1.y, a0);
      a1 = fmaf(c0, w1.z, a1); a1 = fmaf(c1, w1.w, a1); a1 = fmaf(c2, w2.x, a1);
      a1 = fmaf(c3, w2.y, a1); a1 = fmaf(c4, w2.z, a1); a1 = fmaf(c5, w2.w, a1);
      a2 = fmaf(c0, w3.x, a2); a2 = fmaf(c1, w3.y, a2); a2 = fmaf(c2, w3.z, a2);
      a2 = fmaf(c3, w3.w, a2); a2 = fmaf(c4, w4.x, a2); a2 = fmaf(c5, w4.y, a2);
      a3 = fmaf(c0, w4.z, a3); a3 = fmaf(c1, w4.w, a3); a3 = fmaf(c2, w5.x, a3);
      a3 = fmaf(c3, w5.y, a3); a3 = fmaf(c4, w5.z, a3); a3 = fmaf(c5, w5.w, a3);
      h4[j4] = make_float4(fmaxf(a0, 0.f), fmaxf(a1, 0.f), fmaxf(a2, 0.f), fmaxf(a3, 0.f));
    }
    #pragma unroll
    for (int c = 0; c < 16; ++c) {            // 16 B chunks, XOR-swizzled
      float4 lo = h4[c * 2], hi = h4[c * 2 + 1];
      union { unsigned short us[8]; uint4 v; } pk;
      pk.us[0] = f2b(lo.x); pk.us[1] = f2b(lo.y); pk.us[2] = f2b(lo.z); pk.us[3] = f2b(lo.w);
      pk.us[4] = f2b(hi.x); pk.us[5] = f2b(hi.y); pk.us[6] = f2b(hi.z); pk.us[7] = f2b(hi.w);
      int byte = tid * 256 + ((c * 16) ^ ((tid & 7) << 4));
      *(uint4*)(Alds + byte) = pk.v;
    }
  }
  __syncthreads();

  // phase 2: wave computes rows [row0+wid*64, +64) x 256 cols via MFMA
  const int lane = tid & 63, wid = tid >> 6;
  const int g = lane >> 4, cidx = lane & 15;
  float ac[4][4][3] = {};

  for (int chunk = 0; chunk < 4; ++chunk) {
    f32x4 acc[4][4];
    #pragma unroll
    for (int n = 0; n < 4; ++n) {
      float cfv = Cf[chunk * 64 + n * 16 + cidx];
      #pragma unroll
      for (int m = 0; m < 4; ++m) acc[m][n] = (f32x4){cfv, cfv, cfv, cfv};
    }
    #pragma unroll
    for (int ks = 0; ks < 4; ++ks) {
      short8 af[4];
      #pragma unroll
      for (int m = 0; m < 4; ++m) {
        int r = wid * 64 + m * 16 + cidx;
        int byte = r * 256 + ((ks * 64 + g * 16) ^ ((r & 7) << 4));
        af[m] = *(const short8*)(Alds + byte);
      }
      short8 bf[4];
      #pragma unroll
      for (int n = 0; n < 4; ++n)
        bf[n] = *(const short8*)((const char*)Bpack +
                 (((chunk * 4 + ks) * 4 + n) * 1024) + lane * 16);
      #pragma unroll
      for (int m = 0; m < 4; ++m)
        #pragma unroll
        for (int n = 0; n < 4; ++n)
          acc[m][n] = __builtin_amdgcn_mfma_f32_16x16x32_bf16(af[m], bf[n], acc[m][n], 0, 0, 0);
    }
    #pragma unroll
    for (int n = 0; n < 4; ++n) {
      int ot = chunk * 64 + n * 16 + cidx;
      int o = ot >> 1;
      float wc0 = Wc[o], wc1 = Wc[HID + o], wc2 = Wc[2 * HID + o];
      #pragma unroll
      for (int m = 0; m < 4; ++m) {
        #pragma unroll
        for (int i = 0; i < 4; ++i) {
          float v = fmaxf(acc[m][n][i], 0.f);
          ac[m][i][0] = fmaf(v, wc0, ac[m][i][0]);
          ac[m][i][1] = fmaf(v, wc1, ac[m][i][1]);
          ac[m][i][2] = fmaf(v, wc2, ac[m][i][2]);
        }
      }
    }
  }

  const float bc0 = bc[0], bc1 = bc[1], bc2 = bc[2];
  #pragma unroll
  for (int m = 0; m < 4; ++m) {
    #pragma unroll
    for (int i = 0; i < 4; ++i) {
      float s0 = ac[m][i][0], s1 = ac[m][i][1], s2 = ac[m][i][2];
      s0 += __shfl_xor(s0, 2); s0 += __shfl_xor(s0, 4); s0 += __shfl_xor(s0, 8);
      s1 += __shfl_xor(s1, 2); s1 += __shfl_xor(s1, 4); s1 += __shfl_xor(s1, 8);
      s2 += __shfl_xor(s2, 2); s2 += __shfl_xor(s2, 4); s2 += __shfl_xor(s2, 8);
      float o0 = __shfl_xor(s0, 1), o1 = __shfl_xor(s1, 1), o2 = __shfl_xor(s2, 1);
      const bool odd = lane & 1;
      float t00 = odd ? o0 : s0, t01 = odd ? o1 : s1, t02 = odd ? o2 : s2;
      float t10 = odd ? s0 : o0, t11 = odd ? s1 : o1, t12 = odd ? s2 : o2;
      if (cidx == m * 4 + i) {
        int row = row0 + wid * 64 + m * 16 + g * 4 + i;
        float* rp = outp + (size_t)row * 6;
        float px = rp[0], py = rp[1], pz = rp[2];
        rp[0] = px + t00 + bc0; rp[1] = py + t01 + bc1; rp[2] = pz + t02 + bc2;
        rp[3] = px + t10 + bc0; rp[4] = py + t11 + bc1; rp[5] = pz + t12 + bc2;
      }
    }
  }
}

// --- correctness-only fallback if ws too small (no ws use) ------------------
__global__ __launch_bounds__(TPB) void mlp_fallback(
    const float* __restrict__ W1, const float* __restrict__ b1,
    const float* __restrict__ W2, const float* __restrict__ b2,
    const float* __restrict__ Wd, const float* __restrict__ bd,
    const float* __restrict__ Wc, const float* __restrict__ bc,
    float* __restrict__ outp) {
  const int row = blockIdx.x * TPB + threadIdx.x;
  float2* rp = (float2*)(outp + (size_t)row * 6);
  float2 r0 = rp[0], r1 = rp[1], r2 = rp[2];
  float cc[6] = {r0.x, r0.y, r1.x, r1.y, r2.x, r2.y};
  float h[HID];
  for (int j = 0; j < HID; ++j) {
    float a = b1[j];
    for (int c = 0; c < 6; ++c) a = fmaf(cc[c], W1[j * 6 + c], a);
    h[j] = fmaxf(a, 0.f);
  }
  float sd[HID];
  for (int i = 0; i < HID; ++i) {
    float a = b2[i];
    for (int j = 0; j < HID; ++j) a = fmaf(h[j], W2[i * HID + j], a);
    sd[i] = a;
  }
  float ov[3][2] = {};
  for (int oc = 0; oc < HID; ++oc)
    for (int t = 0; t < 2; ++t) {
      float a = bd[oc];
      for (int i = 0; i < HID; ++i) a = fmaf(sd[i], Wd[i * 256 + oc * 2 + t], a);
      a = fmaxf(a, 0.f);
      for (int c = 0; c < 3; ++c) ov[c][t] = fmaf(a, Wc[c * HID + oc], ov[c][t]);
    }
  rp[0] = make_float2(cc[0] + ov[0][0] + bc[0], cc[1] + ov[1][0] + bc[1]);
  rp[1] = make_float2(cc[2] + ov[2][0] + bc[2], cc[0] + ov[0][1] + bc[0]);
  rp[2] = make_float2(cc[1] + ov[1][1] + bc[1], cc[2] + ov[2][1] + bc[2]);
}

extern "C" void kernel_launch(void* const* d_in, const int* in_sizes, int n_in,
                              void* d_out, int out_size, void* d_ws, size_t ws_size,
                              hipStream_t stream) {
  const float* partial   = (const float*)d_in[0];
  const float* predicted = (const float*)d_in[1];
  const float* W1 = (const float*)d_in[2];
  const float* b1 = (const float*)d_in[3];
  const float* W2 = (const float*)d_in[4];
  const float* b2 = (const float*)d_in[5];
  const float* Wd = (const float*)d_in[6];
  const float* bd = (const float*)d_in[7];
  const float* Wc = (const float*)d_in[8];
  const float* bc = (const float*)d_in[9];
  float* outp = (float*)d_out;

  unsigned short* Bpack = (unsigned short*)d_ws;       // 65536 B
  float* Cf = (float*)((char*)d_ws + 65536);           // 1024 B
  const bool fits = ws_size >= (size_t)66560;

  if (fits)
    hipLaunchKernelGGL(prep2_kernel, dim3(128), dim3(TPB), 0, stream,
                       W2, b2, Wd, bd, Bpack, Cf);
  hipLaunchKernelGGL(knn8_kernel, dim3(Bb * 128), dim3(TPB), 0, stream,
                     partial, predicted, outp);
  if (fits)
    hipLaunchKernelGGL(mlp_mfma, dim3((Bb * Nn) / TPB), dim3(TPB), 65536, stream,
                       W1, b1, Bpack, Cf, Wc, bc, outp);
  else
    hipLaunchKernelGGL(mlp_fallback, dim3((Bb * Nn) / TPB), dim3(TPB), 0, stream,
                       W1, b1, W2, b2, Wd, bd, Wc, bc, outp);
}

// Round 10
// 89.220 us; speedup vs baseline: 1.1125x; 1.1092x over previous
//
#include <hip/hip_runtime.h>
#include <hip/hip_bf16.h>
#include <math.h>

#define TPB 256
constexpr int Bb = 8, Mm = 2048, Nn = 8192, HID = 128;
constexpr int KNNB = Bb * 128;                // 1024 knn blocks
constexpr int PREPB = 128;                    // 128 fused prep blocks

typedef __attribute__((ext_vector_type(8))) short short8;
typedef __attribute__((ext_vector_type(4))) float f32x4;

__device__ __forceinline__ int vzero() { int v; asm("v_mov_b32 %0, 0" : "=v"(v)); return v; }
__device__ __forceinline__ float4 ldg4(const float* __restrict__ p, int idx4, int vz) {
  return ((const float4*)p)[idx4 + vz];
}
__device__ __forceinline__ unsigned short f2b(float x) {
  __hip_bfloat16 h = __float2bfloat16(x);
  return *reinterpret_cast<unsigned short*>(&h);
}

// in-place: a = sorted-asc top-8 of union(a,b); a,b sorted-asc top-8 lists
__device__ __forceinline__ void mergeTop8(float a[8], const float b[8]) {
  float w[8];
  #pragma unroll
  for (int i = 0; i < 8; ++i) w[i] = fmaxf(a[i], b[7 - i]);
  #pragma unroll
  for (int i = 0; i < 4; ++i) {
    float lo = fminf(w[i], w[i + 4]); w[i + 4] = fmaxf(w[i], w[i + 4]); w[i] = lo;
  }
  #pragma unroll
  for (int g = 0; g < 8; g += 4)
    #pragma unroll
    for (int i = 0; i < 2; ++i) {
      float lo = fminf(w[g + i], w[g + i + 2]);
      w[g + i + 2] = fmaxf(w[g + i], w[g + i + 2]); w[g + i] = lo;
    }
  #pragma unroll
  for (int i = 0; i < 8; i += 2) {
    float lo = fminf(w[i], w[i + 1]); w[i + 1] = fmaxf(w[i], w[i + 1]); w[i] = lo;
  }
  #pragma unroll
  for (int i = 0; i < 8; ++i) a[i] = w[i];
}
__device__ __forceinline__ float t8of(const float a[8], const float b[8]) {
  float t = fmaxf(a[0], b[7]);
  #pragma unroll
  for (int i = 1; i < 8; ++i) t = fminf(t, fmaxf(a[i], b[7 - i]));
  return t;
}

// In-place ascending insert: step i reads only not-yet-overwritten slots.
#define INSERT8(L, u)                                                          \
  {                                                                            \
    L[0] = __builtin_amdgcn_fmed3f(u, L[0], L[1]);                             \
    L[1] = __builtin_amdgcn_fmed3f(u, L[1], L[2]);                             \
    L[2] = __builtin_amdgcn_fmed3f(u, L[2], L[3]);                             \
    L[3] = __builtin_amdgcn_fmed3f(u, L[3], L[4]);                             \
    L[4] = __builtin_amdgcn_fmed3f(u, L[4], L[5]);                             \
    L[5] = __builtin_amdgcn_fmed3f(u, L[5], L[6]);                             \
    L[6] = __builtin_amdgcn_fmed3f(u, L[6], L[7]);                             \
    L[7] = fmaxf(L[7], u);                                                     \
  }

// --- K1 (fused): blocks [0,1024) = exact 8-NN (knn6 core: 4 queries/lane x
//     16-way M-split, scalar dots, med3 inserts, shfl merge tree);
//     blocks [1024,1152) = weight prep Wf = W2^T·Wd into MFMA-B order. -------
__global__ __launch_bounds__(TPB, 4) void knn_prep_kernel(
    const float* __restrict__ partial, const float* __restrict__ predicted,
    const float* __restrict__ W2, const float* __restrict__ b2,
    const float* __restrict__ Wd, const float* __restrict__ bd,
    unsigned short* __restrict__ Bpack, float* __restrict__ Cf,
    float* __restrict__ outp) {
  __shared__ float4 pts[Mm];                  // 32 KiB {x,y,z,-0.5|p|^2}
  const int tid = threadIdx.x;

  if (blockIdx.x >= KNNB) {                   // ---- fused prep tail ----
    int idx = (blockIdx.x - KNNB) * TPB + tid;          // 0..32767
    int f = idx >> 9, r = idx & 511, lane = r >> 3, j = r & 7;
    int chunk = f >> 4, ks = (f >> 2) & 3, n = f & 3;
    int k   = ks * 32 + (lane >> 4) * 8 + j;
    int col = chunk * 64 + n * 16 + (lane & 15);
    float acc = 0.f;
    for (int i = 0; i < HID; ++i)
      acc = fmaf(W2[i * HID + k], Wd[i * 256 + col], acc);
    Bpack[idx] = f2b(acc);
    if (idx < 256) {
      float c = bd[idx >> 1];
      for (int i = 0; i < HID; ++i) c = fmaf(b2[i], Wd[i * 256 + idx], c);
      Cf[idx] = c;
    }
    return;
  }

  // ---- knn6 core ----
  const int b  = blockIdx.x >> 7;             // 1024 blocks: 8 b x 128 qt
  const int qt = blockIdx.x & 127;
  const float* pb = partial + (size_t)b * Mm * 3;
  for (int i = tid; i < Mm; i += TPB) {
    float x = pb[3 * i], y = pb[3 * i + 1], z = pb[3 * i + 2];
    pts[i] = make_float4(x, y, z, -0.5f * fmaf(x, x, fmaf(y, y, z * z)));
  }
  __syncthreads();

  const int lane = tid & 63, w = tid >> 6;
  const int s = lane & 15, g = lane >> 4;
  const int qbase = qt * 64 + w * 16 + g * 4;          // 4 consecutive queries
  const float4* qp = (const float4*)(predicted + ((size_t)b * Nn + qbase) * 3);
  const float4 qa = qp[0], qb4 = qp[1], qc = qp[2];    // 12 floats -> 4 queries
  const float q0x = qa.x,  q0y = qa.y,  q0z = qa.z;
  const float q1x = qa.w,  q1y = qb4.x, q1z = qb4.y;
  const float q2x = qb4.z, q2y = qb4.w, q2z = qc.x;
  const float q3x = qc.y,  q3y = qc.z,  q3z = qc.w;

  // pass A: per-query ascending top-8 over this lane's 128-candidate subset
  float l0[8], l1[8], l2[8], l3[8];
  #pragma unroll
  for (int i = 0; i < 8; ++i) { l0[i] = -INFINITY; l1[i] = -INFINITY;
                                l2[i] = -INFINITY; l3[i] = -INFINITY; }
  #pragma unroll 4
  for (int mm = 0; mm < 128; ++mm) {
    float4 p = pts[s + 16 * mm];              // 16 addrs/wave, 4-lane multicast
    float u0 = fmaf(q0x, p.x, fmaf(q0y, p.y, fmaf(q0z, p.z, p.w)));
    float u1 = fmaf(q1x, p.x, fmaf(q1y, p.y, fmaf(q1z, p.z, p.w)));
    float u2 = fmaf(q2x, p.x, fmaf(q2y, p.y, fmaf(q2z, p.z, p.w)));
    float u3 = fmaf(q3x, p.x, fmaf(q3y, p.y, fmaf(q3z, p.z, p.w)));
    INSERT8(l0, u0); INSERT8(l1, u1); INSERT8(l2, u2); INSERT8(l3, u3);
  }

  // merge 16 subset lists per query: full merges at d=1,2,4; t8-only at d=8
  #pragma unroll
  for (int dd = 0; dd < 3; ++dd) {
    const int d = 1 << dd;
    float ob[8];
    #pragma unroll
    for (int i = 0; i < 8; ++i) ob[i] = __shfl_xor(l0[i], d);
    mergeTop8(l0, ob);
    #pragma unroll
    for (int i = 0; i < 8; ++i) ob[i] = __shfl_xor(l1[i], d);
    mergeTop8(l1, ob);
    #pragma unroll
    for (int i = 0; i < 8; ++i) ob[i] = __shfl_xor(l2[i], d);
    mergeTop8(l2, ob);
    #pragma unroll
    for (int i = 0; i < 8; ++i) ob[i] = __shfl_xor(l3[i], d);
    mergeTop8(l3, ob);
  }
  float t80, t81, t82, t83;
  {
    float ob[8];
    #pragma unroll
    for (int i = 0; i < 8; ++i) ob[i] = __shfl_xor(l0[i], 8);
    t80 = t8of(l0, ob);
    #pragma unroll
    for (int i = 0; i < 8; ++i) ob[i] = __shfl_xor(l1[i], 8);
    t81 = t8of(l1, ob);
    #pragma unroll
    for (int i = 0; i < 8; ++i) ob[i] = __shfl_xor(l2[i], 8);
    t82 = t8of(l2, ob);
    #pragma unroll
    for (int i = 0; i < 8; ++i) ob[i] = __shfl_xor(l3[i], 8);
    t83 = t8of(l3, ob);
  }

  // pass B: accumulate u >= t8 (exactly the 8 winners unless duplicate ties)
  float a0x = 0.f, a0y = 0.f, a0z = 0.f, c0 = 0.f;
  float a1x = 0.f, a1y = 0.f, a1z = 0.f, c1 = 0.f;
  float a2x = 0.f, a2y = 0.f, a2z = 0.f, c2 = 0.f;
  float a3x = 0.f, a3y = 0.f, a3z = 0.f, c3 = 0.f;
  #pragma unroll 4
  for (int mm = 0; mm < 128; ++mm) {
    float4 p = pts[s + 16 * mm];
    float u0 = fmaf(q0x, p.x, fmaf(q0y, p.y, fmaf(q0z, p.z, p.w)));  // bitwise
    float u1 = fmaf(q1x, p.x, fmaf(q1y, p.y, fmaf(q1z, p.z, p.w)));  //  same as
    float u2 = fmaf(q2x, p.x, fmaf(q2y, p.y, fmaf(q2z, p.z, p.w)));  //  pass A
    float u3 = fmaf(q3x, p.x, fmaf(q3y, p.y, fmaf(q3z, p.z, p.w)));
    float m0 = (u0 >= t80) ? 1.f : 0.f;
    float m1 = (u1 >= t81) ? 1.f : 0.f;
    float m2 = (u2 >= t82) ? 1.f : 0.f;
    float m3 = (u3 >= t83) ? 1.f : 0.f;
    a0x = fmaf(m0, p.x, a0x); a0y = fmaf(m0, p.y, a0y); a0z = fmaf(m0, p.z, a0z); c0 += m0;
    a1x = fmaf(m1, p.x, a1x); a1y = fmaf(m1, p.y, a1y); a1z = fmaf(m1, p.z, a1z); c1 += m1;
    a2x = fmaf(m2, p.x, a2x); a2y = fmaf(m2, p.y, a2y); a2z = fmaf(m2, p.z, a2z); c2 += m2;
    a3x = fmaf(m3, p.x, a3x); a3y = fmaf(m3, p.y, a3y); a3z = fmaf(m3, p.z, a3z); c3 += m3;
  }
  // reduce across the 16 subset lanes
  #pragma unroll
  for (int dd = 0; dd < 4; ++dd) {
    const int d = 1 << dd;
    a0x += __shfl_xor(a0x, d); a0y += __shfl_xor(a0y, d); a0z += __shfl_xor(a0z, d); c0 += __shfl_xor(c0, d);
    a1x += __shfl_xor(a1x, d); a1y += __shfl_xor(a1y, d); a1z += __shfl_xor(a1z, d); c1 += __shfl_xor(c1, d);
    a2x += __shfl_xor(a2x, d); a2y += __shfl_xor(a2y, d); a2z += __shfl_xor(a2z, d); c2 += __shfl_xor(c2, d);
    a3x += __shfl_xor(a3x, d); a3y += __shfl_xor(a3y, d); a3z += __shfl_xor(a3z, d); c3 += __shfl_xor(c3, d);
  }

  // writers: lane s==k writes query qbase+k
  #pragma unroll
  for (int k = 0; k < 4; ++k) {
    if (s == k) {
      float qx = (k == 0) ? q0x : (k == 1) ? q1x : (k == 2) ? q2x : q3x;
      float qy = (k == 0) ? q0y : (k == 1) ? q1y : (k == 2) ? q2y : q3y;
      float qz = (k == 0) ? q0z : (k == 1) ? q1z : (k == 2) ? q2z : q3z;
      float t8 = (k == 0) ? t80 : (k == 1) ? t81 : (k == 2) ? t82 : t83;
      float sx = (k == 0) ? a0x : (k == 1) ? a1x : (k == 2) ? a2x : a3x;
      float sy = (k == 0) ? a0y : (k == 1) ? a1y : (k == 2) ? a2y : a3y;
      float sz = (k == 0) ? a0z : (k == 1) ? a1z : (k == 2) ? a2z : a3z;
      float cn = (k == 0) ? c0  : (k == 1) ? c1  : (k == 2) ? c2  : c3;
      if (cn != 8.0f) {                       // duplicate boundary ties: rare
        sx = sy = sz = 0.f; float cw = 0.f;
        for (int m = 0; m < Mm; ++m) {        // strict winners
          float4 p = pts[m];
          float u = fmaf(qx, p.x, fmaf(qy, p.y, fmaf(qz, p.z, p.w)));
          if (u > t8) { sx += p.x; sy += p.y; sz += p.z; cw += 1.f; }
        }
        int need = 8 - (int)cw, got = 0;
        for (int m = 0; m < Mm && got < need; ++m) {   // earliest == ties
          float4 p = pts[m];
          float u = fmaf(qx, p.x, fmaf(qy, p.y, fmaf(qz, p.z, p.w)));
          if (u == t8) { sx += p.x; sy += p.y; sz += p.z; ++got; }
        }
      }
      float2* co = (float2*)(outp + ((size_t)b * Nn + qbase + k) * 6);
      co[0] = make_float2(qx, qy);
      co[1] = make_float2(qz, sx * 0.125f);
      co[2] = make_float2(sy * 0.125f, sz * 0.125f);
    }
  }
}

// --- standalone prep (fallback path only, when ws fits but knn fused not used)
__global__ __launch_bounds__(TPB) void prep2_kernel(const float* __restrict__ W2,
    const float* __restrict__ b2, const float* __restrict__ Wd,
    const float* __restrict__ bd, unsigned short* __restrict__ Bpack,
    float* __restrict__ Cf) {
  int idx = blockIdx.x * TPB + threadIdx.x;
  int f = idx >> 9, r = idx & 511, lane = r >> 3, j = r & 7;
  int chunk = f >> 4, ks = (f >> 2) & 3, n = f & 3;
  int k   = ks * 32 + (lane >> 4) * 8 + j;
  int col = chunk * 64 + n * 16 + (lane & 15);
  float acc = 0.f;
  for (int i = 0; i < HID; ++i)
    acc = fmaf(W2[i * HID + k], Wd[i * 256 + col], acc);
  Bpack[idx] = f2b(acc);
  if (idx < 256) {
    float c = bd[idx >> 1];
    for (int i = 0; i < HID; ++i) c = fmaf(b2[i], Wd[i * 256 + idx], c);
    Cf[idx] = c;
  }
}

// --- K2: fc1(regs) -> A to LDS(bf16,swizzled) -> MFMA GEMM vs Bpack -> epilogue
__global__ __launch_bounds__(TPB) void mlp_mfma(const float* __restrict__ W1,
    const float* __restrict__ b1, const unsigned short* __restrict__ Bpack,
    const float* __restrict__ Cf, const float* __restrict__ Wc,
    const float* __restrict__ bc, float* __restrict__ outp) {
  extern __shared__ char Alds[];              // 65536 B: A[256 rows][128 k] bf16
  const int tid = threadIdx.x;
  const int row0 = blockIdx.x * TPB;
  const int vz = vzero();

  { // phase 1: fc1 + relu for row = row0 + tid; stage bf16 row to LDS
    const float* rp = outp + (size_t)(row0 + tid) * 6;
    float2 r0 = *(const float2*)rp, r1 = *(const float2*)(rp + 2),
           r2 = *(const float2*)(rp + 4);
    const float c0 = r0.x, c1 = r0.y, c2 = r1.x, c3 = r1.y, c4 = r2.x, c5 = r2.y;
    float4 h4[32];
    #pragma unroll
    for (int j4 = 0; j4 < 32; ++j4) {
      float4 bb = ((const float4*)b1)[j4];
      float4 w0 = ldg4(W1, j4 * 6 + 0, vz), w1 = ldg4(W1, j4 * 6 + 1, vz),
             w2 = ldg4(W1, j4 * 6 + 2, vz), w3 = ldg4(W1, j4 * 6 + 3, vz),
             w4 = ldg4(W1, j4 * 6 + 4, vz), w5 = ldg4(W1, j4 * 6 + 5, vz);
      float a0 = bb.x, a1 = bb.y, a2 = bb.z, a3 = bb.w;
      a0 = fmaf(c0, w0.x, a0); a0 = fmaf(c1, w0.y, a0); a0 = fmaf(c2, w0.z, a0);
      a0 = fmaf(c3, w0.w, a0); a0 = fmaf(c4, w1.x, a0); a0 = fmaf(c5, w1.y, a0);
      a1 = fmaf(c0, w1.z, a1); a1 = fmaf(c1, w1.w, a1); a1 = fmaf(c2, w2.x, a1);
      a1 = fmaf(c3, w2.y, a1); a1 = fmaf(c4, w2.z, a1); a1 = fmaf(c5, w2.w, a1);
      a2 = fmaf(c0, w3.x, a2); a2 = fmaf(c1, w3.y, a2); a2 = fmaf(c2, w3.z, a2);
      a2 = fmaf(c3, w3.w, a2); a2 = fmaf(c4, w4.x, a2); a2 = fmaf(c5, w4.y, a2);
      a3 = fmaf(c0, w4.z, a3); a3 = fmaf(c1, w4.w, a3); a3 = fmaf(c2, w5.x, a3);
      a3 = fmaf(c3, w5.y, a3); a3 = fmaf(c4, w5.z, a3); a3 = fmaf(c5, w5.w, a3);
      h4[j4] = make_float4(fmaxf(a0, 0.f), fmaxf(a1, 0.f), fmaxf(a2, 0.f), fmaxf(a3, 0.f));
    }
    #pragma unroll
    for (int c = 0; c < 16; ++c) {            // 16 B chunks, XOR-swizzled
      float4 lo = h4[c * 2], hi = h4[c * 2 + 1];
      union { unsigned short us[8]; uint4 v; } pk;
      pk.us[0] = f2b(lo.x); pk.us[1] = f2b(lo.y); pk.us[2] = f2b(lo.z); pk.us[3] = f2b(lo.w);
      pk.us[4] = f2b(hi.x); pk.us[5] = f2b(hi.y); pk.us[6] = f2b(hi.z); pk.us[7] = f2b(hi.w);
      int byte = tid * 256 + ((c * 16) ^ ((tid & 7) << 4));
      *(uint4*)(Alds + byte) = pk.v;
    }
  }
  __syncthreads();

  // phase 2: wave computes rows [row0+wid*64, +64) x 256 cols via MFMA
  const int lane = tid & 63, wid = tid >> 6;
  const int g = lane >> 4, cidx = lane & 15;
  float ac[4][4][3] = {};

  for (int chunk = 0; chunk < 4; ++chunk) {
    f32x4 acc[4][4];
    #pragma unroll
    for (int n = 0; n < 4; ++n) {
      float cfv = Cf[chunk * 64 + n * 16 + cidx];
      #pragma unroll
      for (int m = 0; m < 4; ++m) acc[m][n] = (f32x4){cfv, cfv, cfv, cfv};
    }
    #pragma unroll
    for (int ks = 0; ks < 4; ++ks) {
      short8 af[4];
      #pragma unroll
      for (int m = 0; m < 4; ++m) {
        int r = wid * 64 + m * 16 + cidx;
        int byte = r * 256 + ((ks * 64 + g * 16) ^ ((r & 7) << 4));
        af[m] = *(const short8*)(Alds + byte);
      }
      short8 bf[4];
      #pragma unroll
      for (int n = 0; n < 4; ++n)
        bf[n] = *(const short8*)((const char*)Bpack +
                 (((chunk * 4 + ks) * 4 + n) * 1024) + lane * 16);
      #pragma unroll
      for (int m = 0; m < 4; ++m)
        #pragma unroll
        for (int n = 0; n < 4; ++n)
          acc[m][n] = __builtin_amdgcn_mfma_f32_16x16x32_bf16(af[m], bf[n], acc[m][n], 0, 0, 0);
    }
    #pragma unroll
    for (int n = 0; n < 4; ++n) {
      int ot = chunk * 64 + n * 16 + cidx;
      int o = ot >> 1;
      float wc0 = Wc[o], wc1 = Wc[HID + o], wc2 = Wc[2 * HID + o];
      #pragma unroll
      for (int m = 0; m < 4; ++m) {
        #pragma unroll
        for (int i = 0; i < 4; ++i) {
          float v = fmaxf(acc[m][n][i], 0.f);
          ac[m][i][0] = fmaf(v, wc0, ac[m][i][0]);
          ac[m][i][1] = fmaf(v, wc1, ac[m][i][1]);
          ac[m][i][2] = fmaf(v, wc2, ac[m][i][2]);
        }
      }
    }
  }

  const float bc0 = bc[0], bc1 = bc[1], bc2 = bc[2];
  #pragma unroll
  for (int m = 0; m < 4; ++m) {
    #pragma unroll
    for (int i = 0; i < 4; ++i) {
      float s0 = ac[m][i][0], s1 = ac[m][i][1], s2 = ac[m][i][2];
      s0 += __shfl_xor(s0, 2); s0 += __shfl_xor(s0, 4); s0 += __shfl_xor(s0, 8);
      s1 += __shfl_xor(s1, 2); s1 += __shfl_xor(s1, 4); s1 += __shfl_xor(s1, 8);
      s2 += __shfl_xor(s2, 2); s2 += __shfl_xor(s2, 4); s2 += __shfl_xor(s2, 8);
      float o0 = __shfl_xor(s0, 1), o1 = __shfl_xor(s1, 1), o2 = __shfl_xor(s2, 1);
      const bool odd = lane & 1;
      float t00 = odd ? o0 : s0, t01 = odd ? o1 : s1, t02 = odd ? o2 : s2;
      float t10 = odd ? s0 : o0, t11 = odd ? s1 : o1, t12 = odd ? s2 : o2;
      if (cidx == m * 4 + i) {
        int row = row0 + wid * 64 + m * 16 + g * 4 + i;
        float* rp = outp + (size_t)row * 6;
        float px = rp[0], py = rp[1], pz = rp[2];
        rp[0] = px + t00 + bc0; rp[1] = py + t01 + bc1; rp[2] = pz + t02 + bc2;
        rp[3] = px + t10 + bc0; rp[4] = py + t11 + bc1; rp[5] = pz + t12 + bc2;
      }
    }
  }
}

// --- correctness-only fallback if ws too small (no ws use) ------------------
__global__ __launch_bounds__(TPB) void mlp_fallback(
    const float* __restrict__ W1, const float* __restrict__ b1,
    const float* __restrict__ W2, const float* __restrict__ b2,
    const float* __restrict__ Wd, const float* __restrict__ bd,
    const float* __restrict__ Wc, const float* __restrict__ bc,
    float* __restrict__ outp) {
  const int row = blockIdx.x * TPB + threadIdx.x;
  float2* rp = (float2*)(outp + (size_t)row * 6);
  float2 r0 = rp[0], r1 = rp[1], r2 = rp[2];
  float cc[6] = {r0.x, r0.y, r1.x, r1.y, r2.x, r2.y};
  float h[HID];
  for (int j = 0; j < HID; ++j) {
    float a = b1[j];
    for (int c = 0; c < 6; ++c) a = fmaf(cc[c], W1[j * 6 + c], a);
    h[j] = fmaxf(a, 0.f);
  }
  float sd[HID];
  for (int i = 0; i < HID; ++i) {
    float a = b2[i];
    for (int j = 0; j < HID; ++j) a = fmaf(h[j], W2[i * HID + j], a);
    sd[i] = a;
  }
  float ov[3][2] = {};
  for (int oc = 0; oc < HID; ++oc)
    for (int t = 0; t < 2; ++t) {
      float a = bd[oc];
      for (int i = 0; i < HID; ++i) a = fmaf(sd[i], Wd[i * 256 + oc * 2 + t], a);
      a = fmaxf(a, 0.f);
      for (int c = 0; c < 3; ++c) ov[c][t] = fmaf(a, Wc[c * HID + oc], ov[c][t]);
    }
  rp[0] = make_float2(cc[0] + ov[0][0] + bc[0], cc[1] + ov[1][0] + bc[1]);
  rp[1] = make_float2(cc[2] + ov[2][0] + bc[2], cc[0] + ov[0][1] + bc[0]);
  rp[2] = make_float2(cc[1] + ov[1][1] + bc[1], cc[2] + ov[2][1] + bc[2]);
}

extern "C" void kernel_launch(void* const* d_in, const int* in_sizes, int n_in,
                              void* d_out, int out_size, void* d_ws, size_t ws_size,
                              hipStream_t stream) {
  const float* partial   = (const float*)d_in[0];
  const float* predicted = (const float*)d_in[1];
  const float* W1 = (const float*)d_in[2];
  const float* b1 = (const float*)d_in[3];
  const float* W2 = (const float*)d_in[4];
  const float* b2 = (const float*)d_in[5];
  const float* Wd = (const float*)d_in[6];
  const float* bd = (const float*)d_in[7];
  const float* Wc = (const float*)d_in[8];
  const float* bc = (const float*)d_in[9];
  float* outp = (float*)d_out;

  unsigned short* Bpack = (unsigned short*)d_ws;       // 65536 B
  float* Cf = (float*)((char*)d_ws + 65536);           // 1024 B
  const bool fits = ws_size >= (size_t)66560;

  if (fits) {
    // fused: knn blocks [0,1024) + prep blocks [1024,1152)
    hipLaunchKernelGGL(knn_prep_kernel, dim3(KNNB + PREPB), dim3(TPB), 0, stream,
                       partial, predicted, W2, b2, Wd, bd, Bpack, Cf, outp);
    hipLaunchKernelGGL(mlp_mfma, dim3((Bb * Nn) / TPB), dim3(TPB), 65536, stream,
                       W1, b1, Bpack, Cf, Wc, bc, outp);
  } else {
    // no-ws fallback: knn-only grid + direct MLP
    hipLaunchKernelGGL(knn_prep_kernel, dim3(KNNB), dim3(TPB), 0, stream,
                       partial, predicted, W2, b2, Wd, bd,
                       (unsigned short*)nullptr, (float*)nullptr, outp);
    hipLaunchKernelGGL(mlp_fallback, dim3((Bb * Nn) / TPB), dim3(TPB), 0, stream,
                       W1, b1, W2, b2, Wd, bd, Wc, bc, outp);
  }
}